// Round 6
// baseline (408.233 us; speedup 1.0000x reference)
//
#include <hip/hip_runtime.h>
#include <cstdint>

#define BB 8
#define CC 128
#define HH 96
#define WW 160
#define HWsz (HH * WW)                 // 15360
#define TH 8
#define TW 32
#define CSTEP 8
#define HALO_H 16                      // TH + 8
#define SW 48                          // padded halo row stride (40 used + 8 pad), 12 blocks
#define CI_WORDS (HALO_H * SW)         // 768 words = 3 KB per channel
#define BUF_WORDS (CSTEP * CI_WORDS)   // 6144 words = 24 KB per buffer
#define NSLOTS (BUF_WORDS / 64)        // 96 wave-sized staging loads per chunk
#define NSTG 11                        // ceil(96/9) per wave (clamped dup benign)
#define NWAVES 9
#define NTHREADS (NWAVES * 64)         // 576
#define NCHUNKS (CC / CSTEP)           // 16
#define NBLOCKS (BB * (HH / TH) * (WW / TW))  // 480
// LDS pad: total bytes must exceed 81920 so blocks_by_LDS = 1. The backend's
// VGPR budget = 512 / max(LDS-occupancy waves/EU, ceil(9 waves / 4 SIMD)).
// Empirically validated across R0/R3/R4/R5: 48KB->3 blocks->6/EU->budget 84
// (R4/R5 spilled acc[9][8]); 40KB->4 blocks->8/EU->64 (R0); 56KB->2 blocks->
// 4/EU->128 (R3). Pad -> 1 block -> budget clamps at 512/3 ~= 168 > 143 live.
#define LDS_PAD 8256                   // words; total 20544 w = 82176 B > 81920

__device__ __forceinline__ void g2l_dword(const float* g, float* l) {
  __builtin_amdgcn_global_load_lds((const __attribute__((address_space(1))) void*)g,
                                   (__attribute__((address_space(3))) void*)l,
                                   4, 0, 0);
}

// R6 = R5 with ONE change: LDS padded past 80 KB to force 1 block/CU, which
// raises the compiler's LDS-occupancy-derived VGPR budget from 84 to ~168 and
// eliminates the acc[9][8] spill (R4/R5: WRITE 198 MB, 5x output traffic).
// 9 waves/CU suffices because the counted-vmcnt pipeline keeps stage(k+1) in
// flight across barriers (compute ~2000 cyc >> 900 cyc HBM latency) and the
// chunk's critical resource is the LDS pipe (144 b128 x ~14 cyc), not VALU.
extern "C" __global__ void __launch_bounds__(NTHREADS, 1)
corr81_kernel(const float* __restrict__ x1, const float* __restrict__ x2,
              float* __restrict__ out)
{
  __shared__ __align__(16) float lds[2 * BUF_WORDS + LDS_PAD];  // 82176 B

  const int tid  = threadIdx.x;
  const int wv   = tid >> 6;                            // dy 0..8 (wave-uniform)
  const int wvu  = __builtin_amdgcn_readfirstlane(wv);
  const int lane = tid & 63;
  const int h    = lane >> 5;        // channel-half: ci = 4h..4h+3 of the chunk
  const int r    = (lane >> 2) & 7;  // tile row 0..7
  const int s    = lane & 3;         // 8-px col slot (cols 8s..8s+7)

  // XCD-bijective swizzle (validated: FETCH 184->65 MB).
  const int bid0 = blockIdx.x;
  const int bid  = (bid0 & 7) * (NBLOCKS / 8) + (bid0 >> 3);

  const int wt = bid % (WW / TW);
  const int ht = (bid / (WW / TW)) % (HH / TH);
  const int b  = bid / ((WW / TW) * (HH / TH));
  const int h0 = ht * TH;
  const int w0 = wt * TW;

  // ---- chunk-invariant staging offsets, computed ONCE (R2 lesson: never
  // recompute per chunk). Dense linear LDS dest (slot = 64 words); the 4-word
  // block XOR swizzle (block ^ (row&3)) is applied on the GLOBAL source column
  // so source-permute and read-side swizzle are the same involution.
  uint32_t soff[NSTG]; uint32_t doff[NSTG];
#pragma unroll
  for (int i = 0; i < NSTG; ++i) {
    int idx = wvu + 9 * i; if (idx >= NSLOTS) idx = NSLOTS - 1;  // benign dup
    const int e    = idx * 64 + lane;
    const int ci   = e / CI_WORDS;
    const int rem  = e - ci * CI_WORDS;
    const int row  = rem / SW;
    const int colp = rem - row * SW;                 // physical col 0..47
    const int coll = colp ^ ((row & 3) << 2);        // logical col (involution)
    int gh = h0 + row  - 4; gh = gh < 0 ? 0 : (gh > HH - 1 ? HH - 1 : gh);
    int gw = w0 + coll - 4; gw = gw < 0 ? 0 : (gw > WW - 1 ? WW - 1 : gw);
    soff[i] = (uint32_t)((ci * HH + gh) * WW + gw);
    doff[i] = (uint32_t)(idx * 64);                  // wave-uniform -> SGPR
  }

  const float* x2b = x2 + (size_t)b * CC * HWsz;
  // per-lane x1 pointer: channels 4h..4h+3 (+q), row h0+r, cols w0+8s..
  const float* x1c = x1 + ((size_t)b * CC + 4 * h) * HWsz
                        + (size_t)(h0 + r) * WW + (w0 + 8 * s);

  // x2 LDS read bases. Bank algebra: uniform spread at the b128 floor;
  // R4 measured 2.2e6 total conflicts = ~2 cyc/instr (6x down vs R3).
  const int R  = r + wv;             // halo row 0..15
  const int fx = (R & 3) << 2;
  int A[4];
#pragma unroll
  for (int t = 0; t < 4; ++t)
    A[t] = h * (4 * CI_WORDS) + R * SW + ((8 * s + 4 * t) ^ fx);

  float acc[9][8];
#pragma unroll
  for (int d = 0; d < 9; ++d)
#pragma unroll
    for (int p = 0; p < 8; ++p) acc[d][p] = 0.f;

  float4 pf[4][2];   // x1 prefetch regs, all accesses static-indexed (rule #20)

  // ---- prologue: stage(0), then pf(0)  (FIFO: [stage0 11][pf0 8])
#pragma unroll
  for (int i = 0; i < NSTG; ++i) g2l_dword(x2b + soff[i], &lds[doff[i]]);
#pragma unroll
  for (int q = 0; q < 4; ++q) {
    pf[q][0] = *(const float4*)(x1c + (size_t)q * HWsz);
    pf[q][1] = *(const float4*)(x1c + (size_t)q * HWsz + 4);
  }
  x1c += (size_t)CSTEP * HWsz;

#pragma unroll 1
  for (int k = 0; k < NCHUNKS - 1; ++k) {
    // [S] issue stage(k+1) into buf (k+1)&1 — 11 loads, precomputed offsets
    {
      const float* s2 = x2b + (size_t)(k + 1) * (CSTEP * HWsz);
      float* d2 = &lds[((k + 1) & 1) * BUF_WORDS];
#pragma unroll
      for (int i = 0; i < NSTG; ++i) g2l_dword(s2 + soff[i], d2 + doff[i]);
    }

    // [B] counted wait: drains stage(k); keeps pf(k)+stage(k+1) = 19 in flight
    __builtin_amdgcn_sched_barrier(0);
    asm volatile("s_waitcnt vmcnt(19)" ::: "memory");
    __builtin_amdgcn_sched_barrier(0);
    __builtin_amdgcn_s_barrier();
    __builtin_amdgcn_sched_barrier(0);

    // [D] compute chunk k: 16 ds_read_b128 + 288 FMA per lane; x1 from regs
    {
      const float* xb = &lds[(k & 1) * BUF_WORDS];
#pragma unroll
      for (int q = 0; q < 4; ++q) {
        const float4 a0 = pf[q][0];
        const float4 a1 = pf[q][1];
        const float av[8] = {a0.x, a0.y, a0.z, a0.w, a1.x, a1.y, a1.z, a1.w};
        float w16[16];
#pragma unroll
        for (int t = 0; t < 4; ++t) {
          const float4 f = *(const float4*)(xb + A[t] + q * CI_WORDS);
          w16[4*t+0] = f.x; w16[4*t+1] = f.y; w16[4*t+2] = f.z; w16[4*t+3] = f.w;
        }
#pragma unroll
        for (int d = 0; d < 9; ++d)
#pragma unroll
          for (int p = 0; p < 8; ++p)
            acc[d][p] = fmaf(av[p], w16[d + p], acc[d][p]);
      }
      // tail: issue pf(k+1) — lands after stage(k+1) in the vmcnt FIFO, so the
      // wait for pf(k+1) next iter is vmcnt(11): never drains the stage queue.
#pragma unroll
      for (int q = 0; q < 4; ++q) {
        pf[q][0] = *(const float4*)(x1c + (size_t)q * HWsz);
        pf[q][1] = *(const float4*)(x1c + (size_t)q * HWsz + 4);
      }
      x1c += (size_t)CSTEP * HWsz;
    }

    // [C2] WAR barrier
    __builtin_amdgcn_sched_barrier(0);
    __builtin_amdgcn_s_barrier();
    __builtin_amdgcn_sched_barrier(0);
  }

  // ---- peeled last chunk (k = 15, buf 1): nothing left to prefetch
  asm volatile("s_waitcnt vmcnt(0)" ::: "memory");
  __builtin_amdgcn_sched_barrier(0);
  __builtin_amdgcn_s_barrier();
  __builtin_amdgcn_sched_barrier(0);
  {
    const float* xb = &lds[((NCHUNKS - 1) & 1) * BUF_WORDS];
#pragma unroll
    for (int q = 0; q < 4; ++q) {
      const float4 a0 = pf[q][0];
      const float4 a1 = pf[q][1];
      const float av[8] = {a0.x, a0.y, a0.z, a0.w, a1.x, a1.y, a1.z, a1.w};
      float w16[16];
#pragma unroll
      for (int t = 0; t < 4; ++t) {
        const float4 f = *(const float4*)(xb + A[t] + q * CI_WORDS);
        w16[4*t+0] = f.x; w16[4*t+1] = f.y; w16[4*t+2] = f.z; w16[4*t+3] = f.w;
      }
#pragma unroll
      for (int d = 0; d < 9; ++d)
#pragma unroll
        for (int p = 0; p < 8; ++p)
          acc[d][p] = fmaf(av[p], w16[d + p], acc[d][p]);
    }
  }

  // ---- epilogue: combine channel-halves across lane^32 (R1/R4-validated), /8.
  float* op = out + (((size_t)b * 81 + (size_t)wv * 9) * HH + (h0 + r)) * WW
                  + (w0 + 8 * s + 4 * h);
#pragma unroll
  for (int d = 0; d < 9; ++d) {
    const float own0 = h ? acc[d][4] : acc[d][0];
    const float own1 = h ? acc[d][5] : acc[d][1];
    const float own2 = h ? acc[d][6] : acc[d][2];
    const float own3 = h ? acc[d][7] : acc[d][3];
    const float snd0 = h ? acc[d][0] : acc[d][4];
    const float snd1 = h ? acc[d][1] : acc[d][5];
    const float snd2 = h ? acc[d][2] : acc[d][6];
    const float snd3 = h ? acc[d][3] : acc[d][7];
    float4 v;
    v.x = (own0 + __shfl_xor(snd0, 32)) * 0.125f;
    v.y = (own1 + __shfl_xor(snd1, 32)) * 0.125f;
    v.z = (own2 + __shfl_xor(snd2, 32)) * 0.125f;
    v.w = (own3 + __shfl_xor(snd3, 32)) * 0.125f;
    *(float4*)(op + (size_t)d * HWsz) = v;
  }
}

extern "C" void kernel_launch(void* const* d_in, const int* in_sizes, int n_in,
                              void* d_out, int out_size, void* d_ws, size_t ws_size,
                              hipStream_t stream) {
  const float* x1 = (const float*)d_in[0];
  const float* x2 = (const float*)d_in[1];
  float* out = (float*)d_out;
  corr81_kernel<<<dim3(NBLOCKS), dim3(NTHREADS), 0, stream>>>(x1, x2, out);
}

// Round 7
// 391.208 us; speedup vs baseline: 1.0435x; 1.0435x over previous
//
#include <hip/hip_runtime.h>
#include <cstdint>

#define BB 8
#define CC 128
#define HH 96
#define WW 160
#define HWsz (HH * WW)                 // 15360
#define TH 8
#define TW 32
#define CSTEP 8
#define HALO_H 16                      // TH + 8
#define SW 48                          // padded halo row stride (40 used + 8 pad), 12 blocks
#define CI_WORDS (HALO_H * SW)         // 768 words = 3 KB per channel
#define BUF_WORDS (CSTEP * CI_WORDS)   // 6144 words = 24 KB per buffer
#define NSLOTS (BUF_WORDS / 64)        // 96 wave-sized staging loads per chunk
#define NSTG 11                        // ceil(96/9) per wave (clamped dup benign)
#define NWAVES 9
#define NTHREADS (NWAVES * 64)         // 576
#define NCHUNKS (CC / CSTEP)           // 16
#define NBLOCKS (BB * (HH / TH) * (WW / TW))  // 480

__device__ __forceinline__ void g2l_dword(const float* g, float* l) {
  __builtin_amdgcn_global_load_lds((const __attribute__((address_space(1))) void*)g,
                                   (__attribute__((address_space(3))) void*)l,
                                   4, 0, 0);
}

// R7 = R5 body with the resource attributes changed:
//   __launch_bounds__(576,N)  ->  amdgpu_flat_work_group_size(576,576)
//                                 + amdgpu_waves_per_eu(1,4)
// R4/R5/R6 proved the VGPR cap (84 = 512/6) is set by the backend's default
// waves-per-eu target (6), NOT by launch_bounds' 2nd arg (1 vs 2: identical
// binaries) and NOT by LDS occupancy (82 KB pad: still 84). waves_per_eu(1,_)
// lowers the guaranteed-occupancy floor to 1 wave/EU, so the budget becomes
// the launchability bound 512/ceil(9 waves/4 EU) = 170 > ~140 live set ->
// acc[9][8] finally unspilled. Expected residency: VGPR ~150 -> 3 waves/EU
// -> 1 block/CU; per-chunk pipe demands at the 16-b128 shape: VALU ~2.6k,
// LDS ~1.6k (conflicts R4-validated 2.2e6), L2-x1 ~1.3k cyc.
extern "C" __global__ void
__attribute__((amdgpu_flat_work_group_size(NTHREADS, NTHREADS),
               amdgpu_waves_per_eu(1, 4)))
corr81_kernel(const float* __restrict__ x1, const float* __restrict__ x2,
              float* __restrict__ out)
{
  __shared__ __align__(16) float lds[2 * BUF_WORDS];   // 48 KB

  const int tid  = threadIdx.x;
  const int wv   = tid >> 6;                            // dy 0..8 (wave-uniform)
  const int wvu  = __builtin_amdgcn_readfirstlane(wv);
  const int lane = tid & 63;
  const int h    = lane >> 5;        // channel-half: ci = 4h..4h+3 of the chunk
  const int r    = (lane >> 2) & 7;  // tile row 0..7
  const int s    = lane & 3;         // 8-px col slot (cols 8s..8s+7)

  // XCD-bijective swizzle (validated: FETCH 184->65 MB).
  const int bid0 = blockIdx.x;
  const int bid  = (bid0 & 7) * (NBLOCKS / 8) + (bid0 >> 3);

  const int wt = bid % (WW / TW);
  const int ht = (bid / (WW / TW)) % (HH / TH);
  const int b  = bid / ((WW / TW) * (HH / TH));
  const int h0 = ht * TH;
  const int w0 = wt * TW;

  // ---- chunk-invariant staging offsets, computed ONCE (R2 lesson: never
  // recompute per chunk). Dense linear LDS dest (slot = 64 words); the 4-word
  // block XOR swizzle (block ^ (row&3)) is applied on the GLOBAL source column
  // so source-permute and read-side swizzle are the same involution.
  uint32_t soff[NSTG]; uint32_t doff[NSTG];
#pragma unroll
  for (int i = 0; i < NSTG; ++i) {
    int idx = wvu + 9 * i; if (idx >= NSLOTS) idx = NSLOTS - 1;  // benign dup
    const int e    = idx * 64 + lane;
    const int ci   = e / CI_WORDS;
    const int rem  = e - ci * CI_WORDS;
    const int row  = rem / SW;
    const int colp = rem - row * SW;                 // physical col 0..47
    const int coll = colp ^ ((row & 3) << 2);        // logical col (involution)
    int gh = h0 + row  - 4; gh = gh < 0 ? 0 : (gh > HH - 1 ? HH - 1 : gh);
    int gw = w0 + coll - 4; gw = gw < 0 ? 0 : (gw > WW - 1 ? WW - 1 : gw);
    soff[i] = (uint32_t)((ci * HH + gh) * WW + gw);
    doff[i] = (uint32_t)(idx * 64);                  // wave-uniform -> SGPR
  }

  const float* x2b = x2 + (size_t)b * CC * HWsz;
  // per-lane x1 pointer: channels 4h..4h+3 (+q), row h0+r, cols w0+8s..
  const float* x1c = x1 + ((size_t)b * CC + 4 * h) * HWsz
                        + (size_t)(h0 + r) * WW + (w0 + 8 * s);

  // x2 LDS read bases. Bank algebra: uniform spread at the b128 floor;
  // R4 measured 2.2e6 total conflicts = ~2 cyc/instr (6x down vs R3).
  const int R  = r + wv;             // halo row 0..15
  const int fx = (R & 3) << 2;
  int A[4];
#pragma unroll
  for (int t = 0; t < 4; ++t)
    A[t] = h * (4 * CI_WORDS) + R * SW + ((8 * s + 4 * t) ^ fx);

  float acc[9][8];
#pragma unroll
  for (int d = 0; d < 9; ++d)
#pragma unroll
    for (int p = 0; p < 8; ++p) acc[d][p] = 0.f;

  float4 pf[4][2];   // x1 prefetch regs, all accesses static-indexed (rule #20)

  // ---- prologue: stage(0), then pf(0)  (FIFO: [stage0 11][pf0 8])
#pragma unroll
  for (int i = 0; i < NSTG; ++i) g2l_dword(x2b + soff[i], &lds[doff[i]]);
#pragma unroll
  for (int q = 0; q < 4; ++q) {
    pf[q][0] = *(const float4*)(x1c + (size_t)q * HWsz);
    pf[q][1] = *(const float4*)(x1c + (size_t)q * HWsz + 4);
  }
  x1c += (size_t)CSTEP * HWsz;

#pragma unroll 1
  for (int k = 0; k < NCHUNKS - 1; ++k) {
    // [S] issue stage(k+1) into buf (k+1)&1 — 11 loads, precomputed offsets
    {
      const float* s2 = x2b + (size_t)(k + 1) * (CSTEP * HWsz);
      float* d2 = &lds[((k + 1) & 1) * BUF_WORDS];
#pragma unroll
      for (int i = 0; i < NSTG; ++i) g2l_dword(s2 + soff[i], d2 + doff[i]);
    }

    // [B] counted wait: drains stage(k); keeps pf(k)+stage(k+1) = 19 in flight
    __builtin_amdgcn_sched_barrier(0);
    asm volatile("s_waitcnt vmcnt(19)" ::: "memory");
    __builtin_amdgcn_sched_barrier(0);
    __builtin_amdgcn_s_barrier();
    __builtin_amdgcn_sched_barrier(0);

    // [D] compute chunk k: 16 ds_read_b128 + 288 FMA per lane; x1 from regs
    {
      const float* xb = &lds[(k & 1) * BUF_WORDS];
#pragma unroll
      for (int q = 0; q < 4; ++q) {
        const float4 a0 = pf[q][0];
        const float4 a1 = pf[q][1];
        const float av[8] = {a0.x, a0.y, a0.z, a0.w, a1.x, a1.y, a1.z, a1.w};
        float w16[16];
#pragma unroll
        for (int t = 0; t < 4; ++t) {
          const float4 f = *(const float4*)(xb + A[t] + q * CI_WORDS);
          w16[4*t+0] = f.x; w16[4*t+1] = f.y; w16[4*t+2] = f.z; w16[4*t+3] = f.w;
        }
#pragma unroll
        for (int d = 0; d < 9; ++d)
#pragma unroll
          for (int p = 0; p < 8; ++p)
            acc[d][p] = fmaf(av[p], w16[d + p], acc[d][p]);
      }
      // tail: issue pf(k+1) — lands after stage(k+1) in the vmcnt FIFO, so the
      // wait for pf(k+1) next iter is vmcnt(11): never drains the stage queue.
#pragma unroll
      for (int q = 0; q < 4; ++q) {
        pf[q][0] = *(const float4*)(x1c + (size_t)q * HWsz);
        pf[q][1] = *(const float4*)(x1c + (size_t)q * HWsz + 4);
      }
      x1c += (size_t)CSTEP * HWsz;
    }

    // [C2] WAR barrier
    __builtin_amdgcn_sched_barrier(0);
    __builtin_amdgcn_s_barrier();
    __builtin_amdgcn_sched_barrier(0);
  }

  // ---- peeled last chunk (k = 15, buf 1): nothing left to prefetch
  asm volatile("s_waitcnt vmcnt(0)" ::: "memory");
  __builtin_amdgcn_sched_barrier(0);
  __builtin_amdgcn_s_barrier();
  __builtin_amdgcn_sched_barrier(0);
  {
    const float* xb = &lds[((NCHUNKS - 1) & 1) * BUF_WORDS];
#pragma unroll
    for (int q = 0; q < 4; ++q) {
      const float4 a0 = pf[q][0];
      const float4 a1 = pf[q][1];
      const float av[8] = {a0.x, a0.y, a0.z, a0.w, a1.x, a1.y, a1.z, a1.w};
      float w16[16];
#pragma unroll
      for (int t = 0; t < 4; ++t) {
        const float4 f = *(const float4*)(xb + A[t] + q * CI_WORDS);
        w16[4*t+0] = f.x; w16[4*t+1] = f.y; w16[4*t+2] = f.z; w16[4*t+3] = f.w;
      }
#pragma unroll
      for (int d = 0; d < 9; ++d)
#pragma unroll
        for (int p = 0; p < 8; ++p)
          acc[d][p] = fmaf(av[p], w16[d + p], acc[d][p]);
    }
  }

  // ---- epilogue: combine channel-halves across lane^32 (R1/R4-validated), /8.
  float* op = out + (((size_t)b * 81 + (size_t)wv * 9) * HH + (h0 + r)) * WW
                  + (w0 + 8 * s + 4 * h);
#pragma unroll
  for (int d = 0; d < 9; ++d) {
    const float own0 = h ? acc[d][4] : acc[d][0];
    const float own1 = h ? acc[d][5] : acc[d][1];
    const float own2 = h ? acc[d][6] : acc[d][2];
    const float own3 = h ? acc[d][7] : acc[d][3];
    const float snd0 = h ? acc[d][0] : acc[d][4];
    const float snd1 = h ? acc[d][1] : acc[d][5];
    const float snd2 = h ? acc[d][2] : acc[d][6];
    const float snd3 = h ? acc[d][3] : acc[d][7];
    float4 v;
    v.x = (own0 + __shfl_xor(snd0, 32)) * 0.125f;
    v.y = (own1 + __shfl_xor(snd1, 32)) * 0.125f;
    v.z = (own2 + __shfl_xor(snd2, 32)) * 0.125f;
    v.w = (own3 + __shfl_xor(snd3, 32)) * 0.125f;
    *(float4*)(op + (size_t)d * HWsz) = v;
  }
}

extern "C" void kernel_launch(void* const* d_in, const int* in_sizes, int n_in,
                              void* d_out, int out_size, void* d_ws, size_t ws_size,
                              hipStream_t stream) {
  const float* x1 = (const float*)d_in[0];
  const float* x2 = (const float*)d_in[1];
  float* out = (float*)d_out;
  corr81_kernel<<<dim3(NBLOCKS), dim3(NTHREADS), 0, stream>>>(x1, x2, out);
}

// Round 8
// 352.335 us; speedup vs baseline: 1.1587x; 1.1103x over previous
//
#include <hip/hip_runtime.h>
#include <cstdint>

#define BB 8
#define CC 128
#define HH 96
#define WW 160
#define HWsz (HH * WW)                 // 15360
#define TH 8
#define TW 32
#define CSTEP 8
#define HALO_H 16                      // TH + 8
#define HALO_W 40                      // TW + 8
#define CH_WORDS (HALO_H * HALO_W)     // 640
#define X2W (CSTEP * CH_WORDS)         // 5120 words = 20 KB per x2 buffer
#define X1W (CSTEP * TH * TW)          // 2048 words = 8 KB per x1 buffer
#define X2_SLOTS (X2W / 64)            // 80
#define X1_SLOTS (X1W / 64)            // 32
#define NWAVES 9
#define NTHREADS (NWAVES * 64)         // 576
#define NCHUNKS (CC / CSTEP)           // 16
#define NBLOCKS (BB * (HH / TH) * (WW / TW))  // 480
#define X1B (3 * X2W)                  // x1 region base: 15360 words
// LDS total: 3*X2W + 2*X1W = 19456 words = 76 KB -> 2 blocks/CU (152 <= 160)

__device__ __forceinline__ void g2l_dword(const float* g, float* l) {
  __builtin_amdgcn_global_load_lds((const __attribute__((address_space(1))) void*)g,
                                   (__attribute__((address_space(3))) void*)l,
                                   4, 0, 0);
}

// R8: single-barrier, 3-deep-x2 / 2-deep-x1 pipeline on the proven R3 compute
// shape (acc[9][4], 64-80 VGPR, no spill at the fixed 84-reg budget).
//
// Schedule per iter k (one vmcnt + one barrier per chunk; R3 had 2 barriers):
//   [vmcnt(9)]  drains x1(k)+x2(k) (and older), keeps x2(k+1) 9 loads in flight
//   [s_barrier] -> every wave has its stage(k) complete (cross-wave RAW safe)
//   [compute k] x2 from buf3[rc], x1 from buf2[k&1]
//   [issue x1(k+1) -> buf2[(k+1)&1]]  then  [issue x2(k+2) -> buf3[rc+2 mod 3]]
// WAR: issuing wave passed barrier(k) => ALL waves finished compute(k-1), the
// last reader of both destination buffers. Compiler may hoist issues to just
// after the barrier — still after barrier(k), still safe.
// FIFO bookkeeping (steady state, issue order x1-then-x2):
//   pre-barrier outstanding = [x1(k) 4][x2(k+1) 9] (+22 transient at iter 0/1)
//   vmcnt(9) keeps the 9 newest = x2(k+1); drains x1(k) and everything older.
// Last iter peeled with vmcnt(0) (only x1(N-1) outstanding; vmcnt(9) would no-op).
extern "C" __global__ void __launch_bounds__(NTHREADS, 2)
corr81_kernel(const float* __restrict__ x1, const float* __restrict__ x2,
              float* __restrict__ out)
{
  __shared__ __align__(16) float lds[3 * X2W + 2 * X1W];   // 76 KB

  const int tid  = threadIdx.x;
  const int wv   = tid >> 6;                              // dy 0..8 (wave-uniform)
  const int wvu  = __builtin_amdgcn_readfirstlane(wv);
  const int lane = tid & 63;
  const int r    = lane >> 3;    // tile row 0..7
  const int j    = lane & 7;     // w-slot 0..7 (4 px each)

  // XCD-bijective swizzle (validated R1/R2/R3: FETCH 184 -> 65 MB).
  const int bid0 = blockIdx.x;
  const int bid  = (bid0 & 7) * (NBLOCKS / 8) + (bid0 >> 3);

  const int wt = bid % (WW / TW);
  const int ht = (bid / (WW / TW)) % (HH / TH);
  const int b  = bid / ((WW / TW) * (HH / TH));
  const int h0 = ht * TH;
  const int w0 = wt * TW;

  // ---- chunk-invariant staging offsets, computed ONCE (R2 lesson).
  // x2 halo: 80 slots, 9 per wave; idx 80 clamps to 79 (benign dup).
  uint32_t soff2[9]; uint32_t doff2[9];
#pragma unroll
  for (int i = 0; i < 9; ++i) {
    int idx = wvu + 9 * i; if (idx >= X2_SLOTS) idx = X2_SLOTS - 1;
    const int e   = idx * 64 + lane;
    const int ci  = e / CH_WORDS;
    const int rem = e - ci * CH_WORDS;
    const int hr  = rem / HALO_W;
    const int wh  = rem - hr * HALO_W;
    int gh = h0 + hr - 4; gh = gh < 0 ? 0 : (gh > HH - 1 ? HH - 1 : gh);
    int gw = w0 + wh - 4; gw = gw < 0 ? 0 : (gw > WW - 1 ? WW - 1 : gw);
    soff2[i] = (uint32_t)((ci * HH + gh) * WW + gw);
    doff2[i] = (uint32_t)(idx * 64);                      // wave-uniform -> SGPR
  }
  // x1 tile: 32 slots, 4 per wave; idx>=32 clamps to 31 (benign dup).
  uint32_t soff1[4]; uint32_t doff1[4];
#pragma unroll
  for (int i = 0; i < 4; ++i) {
    int idx = wvu + 9 * i; if (idx >= X1_SLOTS) idx = X1_SLOTS - 1;
    const int e   = idx * 64 + lane;
    const int ci  = e >> 8;
    const int rem = e & 255;
    const int row = rem >> 5;
    const int col = rem & 31;
    soff1[i] = (uint32_t)(ci * HWsz + (h0 + row) * WW + (w0 + col));
    doff1[i] = (uint32_t)(idx * 64);
  }

  const float* x2b = x2 + (size_t)b * CC * HWsz;
  const float* x1b = x1 + (size_t)b * CC * HWsz;

  float acc[9][4];
#pragma unroll
  for (int d = 0; d < 9; ++d)
#pragma unroll
    for (int p = 0; p < 4; ++p) acc[d][p] = 0.f;

  const int rowbase = (r + wv) * HALO_W + 4 * j;   // x2 LDS read base (words)
  const int abase   = r * TW + 4 * j;              // x1 LDS read base (words)

  // ---- prologue FIFO: [x2(0) 9][x1(0) 4][x2(1) 9]
#pragma unroll
  for (int i = 0; i < 9; ++i) g2l_dword(x2b + soff2[i], &lds[doff2[i]]);
#pragma unroll
  for (int i = 0; i < 4; ++i) g2l_dword(x1b + soff1[i], &lds[X1B + doff1[i]]);
  {
    const float* s2 = x2b + (size_t)(CSTEP * HWsz);
#pragma unroll
    for (int i = 0; i < 9; ++i) g2l_dword(s2 + soff2[i], &lds[X2W + doff2[i]]);
  }

  int rc = 0;  // word base of x2 compute buffer (rotates 0, X2W, 2*X2W)

#pragma unroll 1
  for (int k = 0; k < NCHUNKS - 1; ++k) {
    // [W] one counted wait + one barrier per chunk
    __builtin_amdgcn_sched_barrier(0);
    asm volatile("s_waitcnt vmcnt(9)" ::: "memory");
    __builtin_amdgcn_sched_barrier(0);
    __builtin_amdgcn_s_barrier();
    __builtin_amdgcn_sched_barrier(0);

    // [D] compute chunk k: 24 x2 + 8 x1 ds_read_b128, 288 FMA per lane
    {
      const float* xb = &lds[rc] + rowbase;
      const float* ab = &lds[X1B + (k & 1) * X1W] + abase;
#pragma unroll
      for (int ci = 0; ci < CSTEP; ++ci) {
        const float4 a4 = *(const float4*)(ab + ci * (TH * TW));
        const float4* wr = (const float4*)(xb + ci * CH_WORDS);
        const float4 f0 = wr[0];
        const float4 f1 = wr[1];
        const float4 f2 = wr[2];
        const float av[4] = {a4.x, a4.y, a4.z, a4.w};
        const float w12[12] = {f0.x, f0.y, f0.z, f0.w,
                               f1.x, f1.y, f1.z, f1.w,
                               f2.x, f2.y, f2.z, f2.w};
#pragma unroll
        for (int d = 0; d < 9; ++d)
#pragma unroll
          for (int p = 0; p < 4; ++p)
            acc[d][p] = fmaf(av[p], w12[d + p], acc[d][p]);
      }
    }

    // [I] issue next stages: x1(k+1) FIRST, then x2(k+2) (FIFO order matters
    // for the vmcnt(9) arithmetic). Safe post-barrier (WAR proof above).
    {
      const float* s1 = x1b + (size_t)(k + 1) * (CSTEP * HWsz);
      float* d1 = &lds[X1B + ((k + 1) & 1) * X1W];
#pragma unroll
      for (int i = 0; i < 4; ++i) g2l_dword(s1 + soff1[i], d1 + doff1[i]);
    }
    if (k + 2 < NCHUNKS) {
      int sc = rc + 2 * X2W; if (sc >= 3 * X2W) sc -= 3 * X2W;
      const float* s2 = x2b + (size_t)(k + 2) * (CSTEP * HWsz);
      float* d2 = &lds[sc];
#pragma unroll
      for (int i = 0; i < 9; ++i) g2l_dword(s2 + soff2[i], d2 + doff2[i]);
    }

    rc += X2W; if (rc == 3 * X2W) rc = 0;
  }

  // ---- peeled last chunk: only x1(N-1) (4 loads) outstanding -> vmcnt(0)
  __builtin_amdgcn_sched_barrier(0);
  asm volatile("s_waitcnt vmcnt(0)" ::: "memory");
  __builtin_amdgcn_sched_barrier(0);
  __builtin_amdgcn_s_barrier();
  __builtin_amdgcn_sched_barrier(0);
  {
    const int k = NCHUNKS - 1;
    const float* xb = &lds[rc] + rowbase;
    const float* ab = &lds[X1B + (k & 1) * X1W] + abase;
#pragma unroll
    for (int ci = 0; ci < CSTEP; ++ci) {
      const float4 a4 = *(const float4*)(ab + ci * (TH * TW));
      const float4* wr = (const float4*)(xb + ci * CH_WORDS);
      const float4 f0 = wr[0];
      const float4 f1 = wr[1];
      const float4 f2 = wr[2];
      const float av[4] = {a4.x, a4.y, a4.z, a4.w};
      const float w12[12] = {f0.x, f0.y, f0.z, f0.w,
                             f1.x, f1.y, f1.z, f1.w,
                             f2.x, f2.y, f2.z, f2.w};
#pragma unroll
      for (int d = 0; d < 9; ++d)
#pragma unroll
        for (int p = 0; p < 4; ++p)
          acc[d][p] = fmaf(av[p], w12[d + p], acc[d][p]);
    }
  }

  // ---- epilogue (R0/R3 verbatim): out[((b*81 + wv*9+d)*H + h0+r)*W + w0+4j], /8
  float* op = out + (((size_t)b * 81 + (size_t)wv * 9) * HH + (h0 + r)) * WW + (w0 + 4 * j);
#pragma unroll
  for (int d = 0; d < 9; ++d) {
    float4 v;
    v.x = acc[d][0] * 0.125f;
    v.y = acc[d][1] * 0.125f;
    v.z = acc[d][2] * 0.125f;
    v.w = acc[d][3] * 0.125f;
    *(float4*)(op + (size_t)d * HWsz) = v;
  }
}

extern "C" void kernel_launch(void* const* d_in, const int* in_sizes, int n_in,
                              void* d_out, int out_size, void* d_ws, size_t ws_size,
                              hipStream_t stream) {
  const float* x1 = (const float*)d_in[0];
  const float* x2 = (const float*)d_in[1];
  float* out = (float*)d_out;
  corr81_kernel<<<dim3(NBLOCKS), dim3(NTHREADS), 0, stream>>>(x1, x2, out);
}

// Round 9
// 202.268 us; speedup vs baseline: 2.0183x; 1.7419x over previous
//
#include <hip/hip_runtime.h>
#include <cstdint>

#define BB 8
#define CC 128
#define HH 96
#define WW 160
#define HWsz (HH * WW)                 // 15360
#define TH 8
#define TW 32
#define CSTEP 8
#define HALO_H 16                      // TH + 8
#define SW2 64                         // x2 row stride in words, POWER OF 2 (bank algebra)
#define CI_WORDS (HALO_H * SW2)        // 1024 words = 4 KB per channel slice
#define X2W (CSTEP * CI_WORDS)         // 8192 words = 32 KB per x2 buffer
#define X1W (CSTEP * TH * TW)          // 2048 words = 8 KB per x1 buffer
#define X2_SLOTS (X2W / 64)            // 128 row-slots per chunk
#define X1_SLOTS (X1W / 64)            // 32
#define NSTG2 15                       // x2 stage loads per wave (uniform, see redirect)
#define NWAVES 9
#define NTHREADS (NWAVES * 64)         // 576
#define NCHUNKS (CC / CSTEP)           // 16
#define NBLOCKS (BB * (HH / TH) * (WW / TW))  // 480
#define X1B (2 * X2W)                  // x1 region base: 16384 words
// LDS total: 2*X2W + 2*X1W = 20480 words = 81920 B exactly -> 2 blocks/CU (160 KiB)

__device__ __forceinline__ void g2l_dword(const float* g, float* l) {
  __builtin_amdgcn_global_load_lds((const __attribute__((address_space(1))) void*)g,
                                   (__attribute__((address_space(3))) void*)l,
                                   4, 0, 0);
}

// R9 = R3's proven 2-barrier counted-vmcnt schedule + SW2=64 swizzled x2 layout.
// Swizzle: phys word l of row holds logical col l ^ ((row&3)<<2) (4-word-block
// XOR, applied on the GLOBAL source column at stage time; read side uses the
// same involution). Power-of-2 row stride makes banks = 4*(((j+t)^m) mod 8)
// full-coverage per m-class -> 2 lanes/bank-group per 16-lane phase = free
// 2-way floor (m136). R2's SW=48 failed this (12-block row aliases mod 8).
// Register discipline (84-budget, R4/R5/R8 lessons): staging addresses =
// SGPR scalar bases (sb2/sb1/doff, wvu-uniform) + 4 shared per-lane col VGPRs
// (gw[4], constant-indexed) + 1 per-lane x1 offset. Live ~60 << 84.
// Slot-clamp: idx>=128 redirects to the wave's OWN slot 0 (same src+dst bytes,
// benign WAW; a swizzled clamp-to-127 dup would race with wrong m -> forbidden).
// Every wave issues exactly 15+4=19 loads/chunk -> vmcnt(19) arithmetic uniform.
extern "C" __global__ void __launch_bounds__(NTHREADS, 2)
corr81_kernel(const float* __restrict__ x1, const float* __restrict__ x2,
              float* __restrict__ out)
{
  __shared__ __align__(16) float lds[2 * X2W + 2 * X1W];   // 81920 B exactly

  const int tid  = threadIdx.x;
  const int wv   = tid >> 6;                              // dy 0..8 (wave-uniform)
  const int wvu  = __builtin_amdgcn_readfirstlane(wv);
  const int lane = tid & 63;
  const int r    = lane >> 3;    // tile row 0..7
  const int j    = lane & 7;     // w-slot 0..7 (4 px each)

  // XCD-bijective swizzle (validated: FETCH 184 -> 65 MB).
  const int bid0 = blockIdx.x;
  const int bid  = (bid0 & 7) * (NBLOCKS / 8) + (bid0 >> 3);

  const int wt = bid % (WW / TW);
  const int ht = (bid / (WW / TW)) % (HH / TH);
  const int b  = bid / ((WW / TW) * (HH / TH));
  const int h0 = ht * TH;
  const int w0 = wt * TW;

  // ---- per-lane staged-column VGPRs, one per slot-group g (m = (wvu+g)&3;
  // slots i use group i&3 because 9 ≡ 1 mod 4). Clamp folds replicate-pad.
  int gw[4];
#pragma unroll
  for (int g = 0; g < 4; ++g) {
    const int m  = (wvu + g) & 3;
    const int cl = lane ^ (m << 2);              // logical col this lane stages
    int gwv = w0 + cl - 4;
    gwv = gwv < 0 ? 0 : (gwv > WW - 1 ? WW - 1 : gwv);
    gw[g] = gwv;
  }
  // slot 14 may be redirected to slot 0 (idx = wvu+126 >= 128 for wvu >= 2):
  const int gw14v = (wvu + 9 * 14 < X2_SLOTS) ? gw[14 & 3] : gw[0];

  // ---- wave-uniform scalar parts of staging addresses (SGPRs).
  int sb2[NSTG2]; uint32_t doff2[NSTG2];
#pragma unroll
  for (int i = 0; i < NSTG2; ++i) {
    int idx = wvu + 9 * i;
    if (idx >= X2_SLOTS) idx = wvu;              // redirect to own slot 0
    const int ci  = idx >> 4;
    const int row = idx & 15;
    int gh = h0 + row - 4; gh = gh < 0 ? 0 : (gh > HH - 1 ? HH - 1 : gh);
    sb2[i]  = (ci * HH + gh) * WW;
    doff2[i] = (uint32_t)(idx * 64);
  }
  // x1: linear layout, no swizzle; clamp-dup (idx->31) benign (same src+dst).
  const int voff1 = (lane & 31) + (lane >> 5) * WW;   // per-lane part (1 VGPR)
  int sb1[4]; uint32_t doff1[4];
#pragma unroll
  for (int i = 0; i < 4; ++i) {
    int idx = wvu + 9 * i; if (idx >= X1_SLOTS) idx = X1_SLOTS - 1;
    const int ci = idx >> 2;
    sb1[i]  = ci * HWsz + (h0 + (idx & 3) * 2) * WW + w0;
    doff1[i] = (uint32_t)(idx * 64);
  }

  const float* x2b = x2 + (size_t)b * CC * HWsz;
  const float* x1b = x1 + (size_t)b * CC * HWsz;

  float acc[9][4];
#pragma unroll
  for (int d = 0; d < 9; ++d)
#pragma unroll
    for (int p = 0; p < 4; ++p) acc[d][p] = 0.f;

  // x2 read bases: phys word = R*64 + 4*((j+t)^m), m = R&3. Contains logical
  // cols 4(j+t)..4(j+t)+3 (XOR on block bits preserves within-block order).
  const int R = r + wv;
  const int m = R & 3;
  int B0 = R * SW2 + (((j + 0) ^ m) << 2);
  int B1 = R * SW2 + (((j + 1) ^ m) << 2);
  int B2 = R * SW2 + (((j + 2) ^ m) << 2);
  const int abase = r * TW + 4 * j;              // x1 LDS read base (words)

  // ---- prologue: stage chunk 0 (15 x2 + 4 x1 = 19 loads, FIFO oldest-first)
#pragma unroll
  for (int i = 0; i < NSTG2 - 1; ++i)
    g2l_dword(x2b + sb2[i] + gw[i & 3], &lds[doff2[i]]);
  g2l_dword(x2b + sb2[14] + gw14v, &lds[doff2[14]]);
#pragma unroll
  for (int i = 0; i < 4; ++i)
    g2l_dword(x1b + sb1[i] + voff1, &lds[X1B + doff1[i]]);

#pragma unroll 1
  for (int k = 0; k < NCHUNKS - 1; ++k) {
    // [A] issue stage(k+1): 15 x2 then 4 x1 (order matters for vmcnt math)
    {
      const float* s2 = x2b + (size_t)(k + 1) * (CSTEP * HWsz);
      const float* s1 = x1b + (size_t)(k + 1) * (CSTEP * HWsz);
      float* d2 = &lds[((k + 1) & 1) * X2W];
      float* d1 = &lds[X1B + ((k + 1) & 1) * X1W];
#pragma unroll
      for (int i = 0; i < NSTG2 - 1; ++i)
        g2l_dword(s2 + sb2[i] + gw[i & 3], d2 + doff2[i]);
      g2l_dword(s2 + sb2[14] + gw14v, d2 + doff2[14]);
#pragma unroll
      for (int i = 0; i < 4; ++i)
        g2l_dword(s1 + sb1[i] + voff1, d1 + doff1[i]);
    }

    // [B] counted wait: drains stage(k)'s 19; keeps stage(k+1)'s 19 in flight
    __builtin_amdgcn_sched_barrier(0);
    asm volatile("s_waitcnt vmcnt(19)" ::: "memory");
    __builtin_amdgcn_sched_barrier(0);
    __builtin_amdgcn_s_barrier();
    __builtin_amdgcn_sched_barrier(0);

    // [D] compute chunk k: 24 x2 + 8 x1 ds_read_b128, 288 FMA per lane
    {
      const float* xb = &lds[(k & 1) * X2W];
      const float* ab = &lds[X1B + (k & 1) * X1W] + abase;
#pragma unroll
      for (int ci = 0; ci < CSTEP; ++ci) {
        const float4 a4 = *(const float4*)(ab + ci * (TH * TW));
        const float4 f0 = *(const float4*)(xb + B0 + ci * CI_WORDS);
        const float4 f1 = *(const float4*)(xb + B1 + ci * CI_WORDS);
        const float4 f2 = *(const float4*)(xb + B2 + ci * CI_WORDS);
        const float av[4] = {a4.x, a4.y, a4.z, a4.w};
        const float w12[12] = {f0.x, f0.y, f0.z, f0.w,
                               f1.x, f1.y, f1.z, f1.w,
                               f2.x, f2.y, f2.z, f2.w};
#pragma unroll
        for (int d = 0; d < 9; ++d)
#pragma unroll
          for (int p = 0; p < 4; ++p)
            acc[d][p] = fmaf(av[p], w12[d + p], acc[d][p]);
      }
    }

    // [C2] WAR barrier
    __builtin_amdgcn_sched_barrier(0);
    __builtin_amdgcn_s_barrier();
    __builtin_amdgcn_sched_barrier(0);
  }

  // ---- peeled last chunk (k = 15, buf 1): nothing left to prefetch
  asm volatile("s_waitcnt vmcnt(0)" ::: "memory");
  __builtin_amdgcn_sched_barrier(0);
  __builtin_amdgcn_s_barrier();
  __builtin_amdgcn_sched_barrier(0);
  {
    const int k = NCHUNKS - 1;
    const float* xb = &lds[(k & 1) * X2W];
    const float* ab = &lds[X1B + (k & 1) * X1W] + abase;
#pragma unroll
    for (int ci = 0; ci < CSTEP; ++ci) {
      const float4 a4 = *(const float4*)(ab + ci * (TH * TW));
      const float4 f0 = *(const float4*)(xb + B0 + ci * CI_WORDS);
      const float4 f1 = *(const float4*)(xb + B1 + ci * CI_WORDS);
      const float4 f2 = *(const float4*)(xb + B2 + ci * CI_WORDS);
      const float av[4] = {a4.x, a4.y, a4.z, a4.w};
      const float w12[12] = {f0.x, f0.y, f0.z, f0.w,
                             f1.x, f1.y, f1.z, f1.w,
                             f2.x, f2.y, f2.z, f2.w};
#pragma unroll
      for (int d = 0; d < 9; ++d)
#pragma unroll
        for (int p = 0; p < 4; ++p)
          acc[d][p] = fmaf(av[p], w12[d + p], acc[d][p]);
    }
  }

  // ---- epilogue (R0/R3 verbatim): out[((b*81 + wv*9+d)*H + h0+r)*W + w0+4j], /8
  float* op = out + (((size_t)b * 81 + (size_t)wv * 9) * HH + (h0 + r)) * WW + (w0 + 4 * j);
#pragma unroll
  for (int d = 0; d < 9; ++d) {
    float4 v;
    v.x = acc[d][0] * 0.125f;
    v.y = acc[d][1] * 0.125f;
    v.z = acc[d][2] * 0.125f;
    v.w = acc[d][3] * 0.125f;
    *(float4*)(op + (size_t)d * HWsz) = v;
  }
}

extern "C" void kernel_launch(void* const* d_in, const int* in_sizes, int n_in,
                              void* d_out, int out_size, void* d_ws, size_t ws_size,
                              hipStream_t stream) {
  const float* x1 = (const float*)d_in[0];
  const float* x2 = (const float*)d_in[1];
  float* out = (float*)d_out;
  corr81_kernel<<<dim3(NBLOCKS), dim3(NTHREADS), 0, stream>>>(x1, x2, out);
}